// Round 2
// baseline (986.618 us; speedup 1.0000x reference)
//
#include <hip/hip_runtime.h>
#include <hip/hip_bf16.h>
#include <stdint.h>

// JointAttention: B=1, L=512(txt), N=4096(img), HID=1536, H=12, D=128
// Round 2: correctness-first. Runtime dtype detection (bf16 vs fp32 inputs),
// register staging (no global_load_lds), rope+scatter fused into qkv epilogue.
// ws (bf16): q[0) k[7077888) v[14155776) o[21233664) -> 56.6 MB.

typedef __attribute__((ext_vector_type(8))) short short8;
typedef __attribute__((ext_vector_type(4))) float floatx4;

#define DEV __device__ __forceinline__

DEV float bf2f(uint16_t s) {
  union { uint32_t u; float f; } v;
  v.u = (uint32_t)s << 16;
  return v.f;
}
DEV uint16_t f2bf(float f) {
  __hip_bfloat16 h = __float2bfloat16(f);
  return __builtin_bit_cast(uint16_t, h);
}

// Distinguish bf16 vs fp32 buffers: for bf16 N(0,1) data, even-indexed u16s
// are bf16 samples (sane exponents). For fp32 data, even u16s are low mantissa
// bits (uniform random exponent field, ~21% "sane"). Majority vote over 64.
DEV bool detect_bf16(const void* p) {
  const uint16_t* u = (const uint16_t*)p;
  int sane = 0;
  for (int i = 0; i < 64; ++i) {
    int e = (u[2 * i] >> 7) & 0xFF;
    sane += (e > 90 && e < 145) ? 1 : 0;
  }
  return sane >= 40;
}

DEV short8 load8(const void* base, long idx, bool bf) {
  if (bf) return *(const short8*)((const uint16_t*)base + idx);
  const floatx4* f = (const floatx4*)((const float*)base + idx);
  floatx4 a = f[0], b = f[1];
  short8 r;
  r[0] = (short)f2bf(a[0]); r[1] = (short)f2bf(a[1]);
  r[2] = (short)f2bf(a[2]); r[3] = (short)f2bf(a[3]);
  r[4] = (short)f2bf(b[0]); r[5] = (short)f2bf(b[1]);
  r[6] = (short)f2bf(b[2]); r[7] = (short)f2bf(b[3]);
  return r;
}

DEV float loadElem(const void* base, long idx, bool bf) {
  return bf ? bf2f(((const uint16_t*)base)[idx]) : ((const float*)base)[idx];
}

// ---------------------------------------------------------------------------
// acc[4][4] for C tile (bm,bn) of A[M,K] * B[N,K]^T via bf16 MFMA.
// 128x128 tile, BK=32, register staging + ds_write_b128, XOR chunk swizzle:
// (row, chunk g) lives at slot g^(row&3) so frag ds_read_b128 is low-conflict.
DEV void gemm_core(const void* A, const void* B, bool abf, bool bbf, long bm,
                   long bn, int K, uint16_t* sA, uint16_t* sB,
                   floatx4 (&acc)[4][4]) {
  const int t = threadIdx.x;
  const int lane = t & 63, wave = t >> 6, l16 = lane & 15, quad = lane >> 4;
  const int srow = t >> 2, c = t & 3, g = c ^ (srow & 3);
  const int wm = (wave >> 1) * 64, wn = (wave & 1) * 64;
  const int fsl = (quad ^ (l16 & 3)) * 8;
  for (int k0 = 0; k0 < K; k0 += 32) {
    short8 a0 = load8(A, (bm + srow) * (long)K + k0 + g * 8, abf);
    short8 a1 = load8(A, (bm + 64 + srow) * (long)K + k0 + g * 8, abf);
    short8 b0 = load8(B, (bn + srow) * (long)K + k0 + g * 8, bbf);
    short8 b1 = load8(B, (bn + 64 + srow) * (long)K + k0 + g * 8, bbf);
    __syncthreads();  // prev-iter frag reads done before overwrite
    *(short8*)(sA + srow * 32 + c * 8) = a0;
    *(short8*)(sA + (64 + srow) * 32 + c * 8) = a1;
    *(short8*)(sB + srow * 32 + c * 8) = b0;
    *(short8*)(sB + (64 + srow) * 32 + c * 8) = b1;
    __syncthreads();
    short8 af[4], bfr[4];
#pragma unroll
    for (int i = 0; i < 4; ++i) {
      af[i] = *(const short8*)(sA + (wm + i * 16 + l16) * 32 + fsl);
      bfr[i] = *(const short8*)(sB + (wn + i * 16 + l16) * 32 + fsl);
    }
#pragma unroll
    for (int i = 0; i < 4; ++i)
#pragma unroll
      for (int j = 0; j < 4; ++j)
        acc[i][j] = __builtin_amdgcn_mfma_f32_16x16x32_bf16(af[i], bfr[j],
                                                            acc[i][j], 0, 0, 0);
  }
}

// ---------------------------------------------------------------------------
// QKV gemm with fused scatter + rope. Block column tile = exactly one
// (tensor t in {q,k,v}, head h): th = blockIdx.x, t = th/12, h = th%12.
// Rope (img q,k only): d and d^1 are in adjacent lanes -> __shfl_xor(v,1).
__global__ __launch_bounds__(256, 2) void qkv_gemm(
    const void* X, const void* W, const void* rope, const void* det,
    uint16_t* qb, uint16_t* kb, uint16_t* vb, int s_base) {
  __shared__ uint16_t sA[128 * 32], sB[128 * 32];
  const bool bf = detect_bf16(det);
  const long bm = (long)blockIdx.y * 128, bn = (long)blockIdx.x * 128;
  floatx4 acc[4][4] = {};
  gemm_core(X, W, bf, bf, bm, bn, 1536, sA, sB, acc);

  const int t = threadIdx.x, lane = t & 63, wave = t >> 6;
  const int l16 = lane & 15, quad = lane >> 4;
  const int wm = (wave >> 1) * 64, wn = (wave & 1) * 64;
  const int th = blockIdx.x;
  const int tt = th / 12, h = th - tt * 12;
  uint16_t* dst = tt == 0 ? qb : (tt == 1 ? kb : vb);
  const bool do_rope = (s_base == 512) && (tt < 2);
#pragma unroll
  for (int i = 0; i < 4; ++i)
#pragma unroll
    for (int j = 0; j < 4; ++j)
#pragma unroll
      for (int r = 0; r < 4; ++r) {
        long srow_g = bm + wm + i * 16 + quad * 4 + r;  // row within this input
        int d = wn + j * 16 + l16;
        float v = acc[i][j][r];
        float p = __shfl_xor(v, 1);  // partner element of the rope pair
        if (do_rope) {
          int dp = d & ~1;
          float cc = loadElem(rope, srow_g * 128 + dp, bf);
          float ss = loadElem(rope, srow_g * 128 + dp + 1, bf);
          v = (d & 1) ? (v * cc + p * ss) : (v * cc - p * ss);
        }
        dst[((long)h * 4608 + (s_base + srow_g)) * 128 + d] = f2bf(v);
      }
}

// ---------------------------------------------------------------------------
// Out-projection gemm: A = attention output (ws, bf16), B = W (input dtype),
// C = d_out in detected output dtype.
__global__ __launch_bounds__(256, 2) void out_gemm(
    const uint16_t* Abf, const void* W, const void* det, void* out,
    long row_off) {
  __shared__ uint16_t sA[128 * 32], sB[128 * 32];
  const bool bf = detect_bf16(det);
  const long bm = (long)blockIdx.y * 128, bn = (long)blockIdx.x * 128;
  floatx4 acc[4][4] = {};
  gemm_core(Abf, W, true, bf, bm, bn, 1536, sA, sB, acc);

  const int t = threadIdx.x, lane = t & 63, wave = t >> 6;
  const int l16 = lane & 15, quad = lane >> 4;
  const int wm = (wave >> 1) * 64, wn = (wave & 1) * 64;
#pragma unroll
  for (int i = 0; i < 4; ++i)
#pragma unroll
    for (int j = 0; j < 4; ++j)
#pragma unroll
      for (int r = 0; r < 4; ++r) {
        long row = bm + wm + i * 16 + quad * 4 + r;
        long col = bn + wn + j * 16 + l16;
        long idx = (row_off + row) * 1536 + col;
        if (bf) ((uint16_t*)out)[idx] = f2bf(acc[i][j][r]);
        else ((float*)out)[idx] = acc[i][j][r];
      }
}

// ---------------------------------------------------------------------------
// Flash attention. Block = (64 q-rows, head); 4 waves x 16 q-rows.
// Per 32-key tile: K staged row-major (chunk slot g^(row&15)); V staged
// transposed sVt[d][key] (chunk-swizzled); P C->A transpose via per-wave
// LDS stash; row-sum via MFMA against all-ones B; row-max via shfl_xor.
__global__ __launch_bounds__(256, 2) void attn(
    const uint16_t* __restrict__ qb, const uint16_t* __restrict__ kb,
    const uint16_t* __restrict__ vb, uint16_t* __restrict__ ob) {
  __shared__ uint16_t sK[32 * 128];
  __shared__ uint16_t sVt[128 * 32];
  __shared__ uint16_t sP[4][16 * 32];

  const int t = threadIdx.x;
  const int lane = t & 63, wave = t >> 6;
  const int l16 = lane & 15, quad = lane >> 4;
  const int h = blockIdx.y;
  const int q0 = blockIdx.x * 64 + wave * 16;

  const uint16_t* Qh = qb + (long)h * 4608 * 128;
  const uint16_t* Kh = kb + (long)h * 4608 * 128;
  const uint16_t* Vh = vb + (long)h * 4608 * 128;

  short8 aq[4];
#pragma unroll
  for (int dk = 0; dk < 4; ++dk)
    aq[dk] = *(const short8*)(Qh + (long)(q0 + l16) * 128 + dk * 32 + quad * 8);

  short8 ones;
#pragma unroll
  for (int j = 0; j < 8; ++j) ones[j] = (short)0x3F80;  // bf16 1.0

  float m_i[4] = {-1e30f, -1e30f, -1e30f, -1e30f};
  floatx4 accL = {};
  floatx4 accO[8] = {};

  // K staging: 8 threads/row, 2 chunks (16B) each; slot = chunk ^ (row&15)
  const int krow = t >> 3;       // 0..31
  const int kc2 = (t & 7) * 2;   // even chunk index (of 16 per row)
  const int ks0 = (kc2 ^ (krow & 15)) * 8;
  const int ks1 = ((kc2 + 1) ^ (krow & 15)) * 8;
  // V staging: key pair x 8 d per thread
  const int vkp = (t & 15) * 2;
  const int vdb = (t >> 4) * 8;

  uint16_t* pw = &sP[wave][0];
  const int pf_off = l16 * 64 + ((quad ^ ((l16 ^ (l16 >> 2)) & 3)) * 16);

  for (int kt = 0; kt < 144; ++kt) {
    const int key0 = kt * 32;
    short8 kv0 = *(const short8*)(Kh + (long)(key0 + krow) * 128 + kc2 * 8);
    short8 kv1 = *(const short8*)(Kh + (long)(key0 + krow) * 128 + kc2 * 8 + 8);
    short8 va = *(const short8*)(Vh + (long)(key0 + vkp) * 128 + vdb);
    short8 vn = *(const short8*)(Vh + (long)(key0 + vkp + 1) * 128 + vdb);
    __syncthreads();  // prev-iter LDS reads complete
    *(short8*)(sK + krow * 128 + ks0) = kv0;
    *(short8*)(sK + krow * 128 + ks1) = kv1;
#pragma unroll
    for (int j = 0; j < 8; ++j) {
      int d = vdb + j;
      int ch = (vkp >> 3) ^ ((d ^ (d >> 2)) & 3);
      uint32_t pack = (uint16_t)va[j] | ((uint32_t)(uint16_t)vn[j] << 16);
      *(uint32_t*)((char*)sVt + d * 64 + ch * 16 + (vkp & 7) * 2) = pack;
    }
    __syncthreads();

    // S = Q K^T
    floatx4 sc[2] = {};
#pragma unroll
    for (int ns = 0; ns < 2; ++ns) {
      const int row = ns * 16 + l16;
#pragma unroll
      for (int dk = 0; dk < 4; ++dk) {
        short8 bk =
            *(const short8*)(sK + row * 128 + (((dk * 4 + quad) ^ l16) * 8));
        sc[ns] = __builtin_amdgcn_mfma_f32_16x16x32_bf16(aq[dk], bk, sc[ns],
                                                         0, 0, 0);
      }
    }

    // online softmax
    float alpha[4];
#pragma unroll
    for (int r = 0; r < 4; ++r) {
      float s0 = sc[0][r] * 0.08838834764831845f;
      float s1 = sc[1][r] * 0.08838834764831845f;
      float mx = fmaxf(s0, s1);
      mx = fmaxf(mx, __shfl_xor(mx, 1));
      mx = fmaxf(mx, __shfl_xor(mx, 2));
      mx = fmaxf(mx, __shfl_xor(mx, 4));
      mx = fmaxf(mx, __shfl_xor(mx, 8));
      float mn = fmaxf(m_i[r], mx);
      alpha[r] = __expf(m_i[r] - mn);
      m_i[r] = mn;
      sc[0][r] = __expf(s0 - mn);
      sc[1][r] = __expf(s1 - mn);
    }

    // P -> per-wave stash (C->A transpose), chunk-swizzled
#pragma unroll
    for (int ns = 0; ns < 2; ++ns)
#pragma unroll
      for (int r = 0; r < 4; ++r) {
        const int row = quad * 4 + r;
        const int col = ns * 16 + l16;
        const int ch = (col >> 3) ^ ((row ^ (row >> 2)) & 3);
        *(uint16_t*)((char*)pw + row * 64 + ch * 16 + (col & 7) * 2) =
            f2bf(sc[ns][r]);
      }
    asm volatile("s_waitcnt lgkmcnt(0)" ::: "memory");  // same-wave stash drain

#pragma unroll
    for (int vt = 0; vt < 8; ++vt)
#pragma unroll
      for (int r = 0; r < 4; ++r) accO[vt][r] *= alpha[r];
#pragma unroll
    for (int r = 0; r < 4; ++r) accL[r] *= alpha[r];

    short8 pf = *(const short8*)((char*)pw + pf_off);
    accL = __builtin_amdgcn_mfma_f32_16x16x32_bf16(pf, ones, accL, 0, 0, 0);
#pragma unroll
    for (int vt = 0; vt < 8; ++vt) {
      const int d = vt * 16 + l16;
      short8 bv = *(const short8*)((char*)sVt + d * 64 +
                                   ((quad ^ ((d ^ (d >> 2)) & 3)) * 16));
      accO[vt] = __builtin_amdgcn_mfma_f32_16x16x32_bf16(pf, bv, accO[vt],
                                                         0, 0, 0);
    }
  }

#pragma unroll
  for (int r = 0; r < 4; ++r) {
    const long row = q0 + quad * 4 + r;
    const float inv = 1.f / accL[r];
#pragma unroll
    for (int vt = 0; vt < 8; ++vt)
      ob[row * 1536 + h * 128 + vt * 16 + l16] =
          f2bf(accO[vt][r] * inv);
  }
}

// ---------------------------------------------------------------------------
extern "C" void kernel_launch(void* const* d_in, const int* in_sizes, int n_in,
                              void* d_out, int out_size, void* d_ws,
                              size_t ws_size, hipStream_t stream) {
  const void* txt = d_in[0];
  const void* img = d_in[1];
  const void* rope = d_in[2];
  const void* Wtq = d_in[3];
  const void* Wiq = d_in[4];
  const void* Wto = d_in[5];
  const void* Wio = d_in[6];

  uint16_t* ws = (uint16_t*)d_ws;
  uint16_t* qb = ws;                  // [12][4608][128]
  uint16_t* kb = ws + 7077888;
  uint16_t* vb = ws + 14155776;
  uint16_t* ob = ws + 21233664;       // [4608][1536]

  qkv_gemm<<<dim3(36, 4), 256, 0, stream>>>(txt, Wtq, rope, txt, qb, kb, vb, 0);
  qkv_gemm<<<dim3(36, 32), 256, 0, stream>>>(img, Wiq, rope, txt, qb, kb, vb,
                                             512);
  attn<<<dim3(72, 12), 256, 0, stream>>>(qb, kb, vb, ob);
  out_gemm<<<dim3(12, 4), 256, 0, stream>>>(ob, Wto, txt, d_out, 0);
  out_gemm<<<dim3(12, 32), 256, 0, stream>>>(ob + (long)512 * 1536, Wio, txt,
                                             d_out, 512);
}